// Round 9
// baseline (112.997 us; speedup 1.0000x reference)
//
#include <hip/hip_runtime.h>
#include <math.h>

static constexpr int TPB   = 256;
static constexpr int MPB   = 2048;        // members per seg block
static constexpr int WMEM  = 512;         // members per wave
static constexpr int PMEM  = 256;         // members per phase (2 phases/wave)
static constexpr int LOCAL_BINS = 448;    // span/block ~43 typical; global fallback covers overflow
static constexpr int STAGE_F4   = 200;    // 192 data + 8 pad (one per 24 f4)
static constexpr int ROWS_PER_BLOCK = 32; // mlp: 4 waves x 8 rows

// ---------------------------------------------------------------------------
// Workspace zero (rocclr fillBufferAligned is slow for small fills).
// ---------------------------------------------------------------------------
__global__ __launch_bounds__(256)
void zero_ws_kernel(float4* __restrict__ ws, int n4) {
  int i = blockIdx.x * blockDim.x + threadIdx.x;
  int stride = gridDim.x * blockDim.x;
  for (; i < n4; i += stride) ws[i] = make_float4(0.f, 0.f, 0.f, 0.f);
}

// ---------------------------------------------------------------------------
// Fused kernel, Bresenham role interleave (R8 geometry).
//
// seg role: 2048 members/block, LDS bins, 2 block barriers. NEW in R9:
//   every global load is perfectly coalesced (16B/lane, stride-16).
//   pos is bulk-copied into a per-wave LDS stage (padded layout j+j/24 to
//   break the 12-float read-stride bank conflict), consumed wave-locally
//   (LDS ops of one wave execute in order; lgkmcnt(0) + compiler fence).
//   idx/lm: int4/float4 per thread = stride-16 coalesced. CHUNK=4, 2 phases.
// mlp role: unchanged from R8 (2 quads/wave, 8 outstanding loads/lane).
// ---------------------------------------------------------------------------
__global__ __launch_bounds__(TPB)
void fused_kernel(const float* __restrict__ lm,
                  const float* __restrict__ pos,
                  const int*   __restrict__ idx,
                  const float* __restrict__ gf,
                  const float* __restrict__ w,
                  const float* __restrict__ bptr,
                  const float* __restrict__ noise,
                  const int*   __restrict__ temp_ptr,
                  float* __restrict__ seg_sum,     // [G]
                  float* __restrict__ center_raw,  // [3G]
                  float* __restrict__ out,         // [5G]
                  int M, int G, int nseg, int ntot) {
  __shared__ float  bins[LOCAL_BINS * 4];
  __shared__ float4 stage[4][STAGE_F4];

  long long r = blockIdx.x;
  int segcum  = (int)((r * (long long)nseg) / ntot);
  int segcum1 = (int)(((r + 1) * (long long)nseg) / ntot);

  if (segcum1 != segcum) {
    // ---------------- seg role ----------------
    int blockBase = segcum * MPB;
    if (blockBase >= M) return;
    int blockEnd = min(blockBase + MPB, M);
    int g_first = idx[blockBase];
    int g_last  = idx[blockEnd - 1];
    int span    = g_last - g_first + 1;
    int nbins   = min(span, LOCAL_BINS);

    for (int i = threadIdx.x; i < nbins * 4; i += TPB) bins[i] = 0.f;
    __syncthreads();

    int wid  = threadIdx.x >> 6;
    int lane = threadIdx.x & 63;

    auto flush = [&](int g, float se, float sx, float sy, float sz) {
      int off = g - g_first;
      if (off < LOCAL_BINS) {
        unsafeAtomicAdd(&bins[off*4+0], se);
        unsafeAtomicAdd(&bins[off*4+1], sx);
        unsafeAtomicAdd(&bins[off*4+2], sy);
        unsafeAtomicAdd(&bins[off*4+3], sz);
      } else {               // span-overflow fallback (statistically ~never)
        unsafeAtomicAdd(&seg_sum[g], se);
        unsafeAtomicAdd(&center_raw[3*g+0], sx);
        unsafeAtomicAdd(&center_raw[3*g+1], sy);
        unsafeAtomicAdd(&center_raw[3*g+2], sz);
      }
    };

    #pragma unroll
    for (int h = 0; h < 2; h++) {
      int memBase = blockBase + wid * WMEM + h * PMEM;
      if (memBase < M) {
        if (memBase + PMEM <= M) {
          // -------- full phase: all loads coalesced --------
          const float4* p4 = (const float4*)(pos + (size_t)memBase * 3);
          #pragma unroll
          for (int k = 0; k < 3; k++) {
            int j = lane + 64 * k;
            stage[wid][j + j / 24] = p4[j];
          }
          const int4*   i4 = (const int4*)(idx + memBase);
          const float4* l4 = (const float4*)(lm + memBase);
          int4   ib = i4[lane];
          float4 lv = l4[lane];
          asm volatile("s_waitcnt lgkmcnt(0)" ::: "memory");
          int j0 = 3 * lane;
          float4 s0 = stage[wid][j0     +  j0      / 24];
          float4 s1 = stage[wid][j0 + 1 + (j0 + 1) / 24];
          float4 s2 = stage[wid][j0 + 2 + (j0 + 2) / 24];

          float eb[4];
          eb[0] = __expf(lv.x); eb[1] = __expf(lv.y);
          eb[2] = __expf(lv.z); eb[3] = __expf(lv.w);
          int   ibv[4] = {ib.x, ib.y, ib.z, ib.w};
          float px[4] = {s0.x, s0.w, s1.z, s2.y};
          float py[4] = {s0.y, s1.x, s1.w, s2.z};
          float pz[4] = {s0.z, s1.y, s2.x, s2.w};

          if (ib.x == ib.w) {
            // fast path (~92%): all 4 members in one segment
            float se = eb[0]+eb[1]+eb[2]+eb[3];
            float sx = px[0]*eb[0]+px[1]*eb[1]+px[2]*eb[2]+px[3]*eb[3];
            float sy = py[0]*eb[0]+py[1]*eb[1]+py[2]*eb[2]+py[3]*eb[3];
            float sz = pz[0]*eb[0]+pz[1]*eb[1]+pz[2]*eb[2]+pz[3]*eb[3];
            flush(ib.x, se, sx, sy, sz);
          } else {
            int cur = ibv[0];
            float se = 0.f, sx = 0.f, sy = 0.f, sz = 0.f;
            #pragma unroll
            for (int j = 0; j < 4; j++) {
              if (ibv[j] != cur) {
                flush(cur, se, sx, sy, sz);
                cur = ibv[j]; se = 0.f; sx = 0.f; sy = 0.f; sz = 0.f;
              }
              se += eb[j];
              sx += px[j] * eb[j];
              sy += py[j] * eb[j];
              sz += pz[j] * eb[j];
            }
            flush(cur, se, sx, sy, sz);
          }
        } else {
          // -------- ragged tail phase (last block only): scalar loads --------
          int mstart = memBase + 4 * lane;
          if (mstart < M) {
            int nj = min(4, M - mstart);
            int cur = idx[mstart];
            float se = 0.f, sx = 0.f, sy = 0.f, sz = 0.f;
            for (int j = 0; j < nj; j++) {
              int m = mstart + j;
              int g = idx[m];
              float e = __expf(lm[m]);
              if (g != cur) {
                flush(cur, se, sx, sy, sz);
                cur = g; se = 0.f; sx = 0.f; sy = 0.f; sz = 0.f;
              }
              se += e;
              sx += pos[(size_t)m*3+0] * e;
              sy += pos[(size_t)m*3+1] * e;
              sz += pos[(size_t)m*3+2] * e;
            }
            flush(cur, se, sx, sy, sz);
          }
        }
      }
      // wave-local phase boundary: LDS in-order pipe makes phase-2 writes
      // safe after phase-1 reads; fence keeps the compiler honest.
      asm volatile("" ::: "memory");
    }
    __syncthreads();

    for (int i = threadIdx.x; i < nbins; i += TPB) {
      int g = g_first + i;
      float s0 = bins[i*4+0], s1 = bins[i*4+1], s2 = bins[i*4+2], s3 = bins[i*4+3];
      if (g == g_first || g == g_last) {
        unsafeAtomicAdd(&seg_sum[g], s0);
        unsafeAtomicAdd(&center_raw[3*g+0], s1);
        unsafeAtomicAdd(&center_raw[3*g+1], s2);
        unsafeAtomicAdd(&center_raw[3*g+2], s3);
      } else {
        seg_sum[g] = s0;
        center_raw[3*g+0] = s1;
        center_raw[3*g+1] = s2;
        center_raw[3*g+2] = s3;
      }
    }
  } else {
    // ---------------- mlp role: 2 quads per wave (R8) ----------------
    int mb   = (int)(r - segcum);
    int wid  = threadIdx.x >> 6;
    int lane = threadIdx.x & 63;
    int sub  = lane & 15;
    int rg   = lane >> 4;

    int row0 = (mb * 4 + wid) * 8;
    int rowA = row0 + rg;
    int rowB = row0 + 4 + rg;

    const float4* w4 = (const float4*)w;
    float4 wv0 = w4[sub +  0], wv1 = w4[sub + 16],
           wv2 = w4[sub + 32], wv3 = w4[sub + 48];

    float dA = 0.f, dB = 0.f;
    if (rowA < G) {
      const float4* ga = (const float4*)(gf + (size_t)rowA * 256);
      const float4* gb = (const float4*)(gf + (size_t)rowB * 256);
      float4 a0 = ga[sub +  0], a1 = ga[sub + 16],
             a2 = ga[sub + 32], a3 = ga[sub + 48];
      float4 b0 = gb[sub +  0], b1 = gb[sub + 16],
             b2 = gb[sub + 32], b3 = gb[sub + 48];
      dA  = a0.x*wv0.x + a0.y*wv0.y + a0.z*wv0.z + a0.w*wv0.w;
      dA += a1.x*wv1.x + a1.y*wv1.y + a1.z*wv1.z + a1.w*wv1.w;
      dA += a2.x*wv2.x + a2.y*wv2.y + a2.z*wv2.z + a2.w*wv2.w;
      dA += a3.x*wv3.x + a3.y*wv3.y + a3.z*wv3.z + a3.w*wv3.w;
      dB  = b0.x*wv0.x + b0.y*wv0.y + b0.z*wv0.z + b0.w*wv0.w;
      dB += b1.x*wv1.x + b1.y*wv1.y + b1.z*wv1.z + b1.w*wv1.w;
      dB += b2.x*wv2.x + b2.y*wv2.y + b2.z*wv2.z + b2.w*wv2.w;
      dB += b3.x*wv3.x + b3.y*wv3.y + b3.z*wv3.z + b3.w*wv3.w;
    }
    #pragma unroll
    for (int m = 8; m >= 1; m >>= 1) {
      dA += __shfl_xor(dA, m, 64);
      dB += __shfl_xor(dB, m, 64);
    }

    if (sub == 0 && rowA < G) {
      float bb = bptr[0];
      int iv = temp_ptr[0];
      float tT = (iv > -(1 << 23) && iv < (1 << 23)) ? (float)iv : __int_as_float(iv);

      float logitA = 8.8f * tanhf(dA + bb);
      float nA = noise[rowA];
      float xA = (logitA + (logf(nA) - log1pf(-nA))) / tT;
      out[rowA]     = fminf(xA, 0.f) - log1pf(expf(-fabsf(xA)));
      out[G + rowA] = logitA;

      if (rowB < G) {
        float logitB = 8.8f * tanhf(dB + bb);
        float nB = noise[rowB];
        float xB = (logitB + (logf(nB) - log1pf(-nB))) / tT;
        out[rowB]     = fminf(xB, 0.f) - log1pf(expf(-fabsf(xB)));
        out[G + rowB] = logitB;
      }
    }
  }
}

// ---------------------------------------------------------------------------
// Center normalize: out[2G + i] = center_raw[i] / seg_sum[i/3] (0 if empty).
// ---------------------------------------------------------------------------
__global__ __launch_bounds__(256)
void norm_kernel(const float* __restrict__ seg_sum,
                 const float* __restrict__ center_raw,
                 float* __restrict__ out, int G) {
  int i = blockIdx.x * blockDim.x + threadIdx.x;
  int n = 3 * G;
  if (i < n) {
    int g = i / 3;
    float s = seg_sum[g];
    float inv = (s > 0.f) ? (1.f / s) : 0.f;
    out[(size_t)2 * G + i] = center_raw[i] * inv;
  }
}

extern "C" void kernel_launch(void* const* d_in, const int* in_sizes, int n_in,
                              void* d_out, int out_size, void* d_ws, size_t ws_size,
                              hipStream_t stream) {
  const float* gf    = (const float*)d_in[0];
  const float* pos   = (const float*)d_in[1];
  const float* lm    = (const float*)d_in[2];
  const int*   idx   = (const int*)  d_in[3];
  const float* w     = (const float*)d_in[4];
  const float* b     = (const float*)d_in[5];
  const float* noise = (const float*)d_in[6];
  const int*   temp  = (const int*)  d_in[7];
  float* out = (float*)d_out;

  int G = in_sizes[6];
  int M = in_sizes[3];

  float* seg_sum    = (float*)d_ws;
  float* center_raw = seg_sum + G;

  int n4 = (4 * G) / 4;
  hipLaunchKernelGGL(zero_ws_kernel, dim3(784), dim3(256), 0, stream,
                     (float4*)d_ws, n4);

  int nseg = (M + MPB - 1) / MPB;                          // 4688
  int nmlp = (G + ROWS_PER_BLOCK - 1) / ROWS_PER_BLOCK;    // 6250
  int ntot = nseg + nmlp;
  hipLaunchKernelGGL(fused_kernel, dim3(ntot), dim3(TPB), 0, stream,
                     lm, pos, idx, gf, w, b, noise, temp,
                     seg_sum, center_raw, out, M, G, nseg, ntot);

  int nblk = (3 * G + 255) / 256;
  hipLaunchKernelGGL(norm_kernel, dim3(nblk), dim3(256), 0, stream,
                     seg_sum, center_raw, out, G);
}